// Round 15
// baseline (1053.017 us; speedup 1.0000x reference)
//
#include <hip/hip_runtime.h>
#include <hip/hip_bf16.h>
#include <math.h>

// Dims (fixed): B=16, S=1024, N=16384, DM=512, H=8, D=64, F=256, L=4
#define NTOK 16384
#define BATCH 16
#define SEQ 1024
#define DMODEL 512
#define NHEAD 8
#define HDIM 64
#define FDIM 256
#define BH_TOT 128
#define SCALE_QK 0.3535533905932738f   // 64^-0.25
#define SCALE2 0.125f                  // SCALE_QK^2
#define FSCALE 0.0625f                 // 256^-0.5

typedef __bf16 bf16x8_t __attribute__((ext_vector_type(8)));
typedef float f32x4_t  __attribute__((ext_vector_type(4)));
typedef unsigned short u16x8 __attribute__((ext_vector_type(8)));
typedef unsigned short u16x4 __attribute__((ext_vector_type(4)));
typedef const __attribute__((address_space(1))) char* gas_t;
typedef __attribute__((address_space(3))) char* las_t;

__device__ __forceinline__ float b2f(unsigned short u) {
    union { unsigned int i; float f; } c; c.i = ((unsigned int)u) << 16; return c.f;
}
__device__ __forceinline__ unsigned short f2bu(float f) {
    __hip_bfloat16 h = __float2bfloat16(f);
    return *(unsigned short*)&h;
}
__device__ __forceinline__ bf16x8_t u2b8(u16x8 u) {
    union { u16x8 a; bf16x8_t b; } c; c.a = u; return c.b;
}

// ---------------------------------------------------------------- ALL weight conversions in ONE kernel (7 convT segments + omega)
__global__ __launch_bounds__(256) void convT_all_kernel(
    const float* __restrict__ enc_w2, const float* __restrict__ wq,
    const float* __restrict__ wk, const float* __restrict__ wv,
    const float* __restrict__ wo, const float* __restrict__ w1,
    const float* __restrict__ w2, const float* __restrict__ omega,
    unsigned short* __restrict__ enc_w2t, unsigned short* __restrict__ wqkvt,
    unsigned short* __restrict__ wot, unsigned short* __restrict__ w1t,
    unsigned short* __restrict__ w2t, unsigned short* __restrict__ omT)
{
    int blk = blockIdx.x;
    int t = threadIdx.x;
    if (blk >= 8320) {   // omega: [L][64][128] f32 -> [L][128][64] bf16 * SCALE_QK
        int i = (blk - 8320) * 256 + t;
        int l = i >> 13, rem = i & 8191;
        int f = rem >> 6, d = rem & 63;
        omT[(size_t)l * 8192 + f * 64 + d] =
            f2bu(omega[(size_t)l * 8192 + d * 128 + f] * SCALE_QK);
        return;
    }
    const float* src; unsigned short* dst;
    int K, N, tpl_sh, nx_sh; size_t in_ls, out_ls; int rem;
    if (blk < 128)       { src = enc_w2; dst = enc_w2t;        K = 256;  N = 512;  tpl_sh = 7; nx_sh = 4; in_ls = 0;      out_ls = 0;      rem = blk; }
    else if (blk < 1152) { src = wq;     dst = wqkvt;          K = 512;  N = 512;  tpl_sh = 8; nx_sh = 4; in_ls = 262144; out_ls = 786432; rem = blk - 128; }
    else if (blk < 2176) { src = wk;     dst = wqkvt + 262144; K = 512;  N = 512;  tpl_sh = 8; nx_sh = 4; in_ls = 262144; out_ls = 786432; rem = blk - 1152; }
    else if (blk < 3200) { src = wv;     dst = wqkvt + 524288; K = 512;  N = 512;  tpl_sh = 8; nx_sh = 4; in_ls = 262144; out_ls = 786432; rem = blk - 2176; }
    else if (blk < 4224) { src = wo;     dst = wot;            K = 512;  N = 512;  tpl_sh = 8; nx_sh = 4; in_ls = 262144; out_ls = 262144; rem = blk - 3200; }
    else if (blk < 6272) { src = w1;     dst = w1t;            K = 512;  N = 1024; tpl_sh = 9; nx_sh = 5; in_ls = 524288; out_ls = 524288; rem = blk - 4224; }
    else                 { src = w2;     dst = w2t;            K = 1024; N = 512;  tpl_sh = 9; nx_sh = 4; in_ls = 524288; out_ls = 524288; rem = blk - 6272; }
    int l = rem >> tpl_sh;
    int tt = rem & ((1 << tpl_sh) - 1);
    int ty = tt >> nx_sh, txi = tt & ((1 << nx_sh) - 1);
    src += (size_t)l * in_ls;
    dst += (size_t)l * out_ls;
    int k0 = ty * 32, n0 = txi * 32;

    __shared__ float tile[32][33];
    int r = t >> 3, c4 = (t & 7) * 4;
    float4 v = *(const float4*)(src + (size_t)(k0 + r) * N + n0 + c4);
    tile[r][c4 + 0] = v.x; tile[r][c4 + 1] = v.y;
    tile[r][c4 + 2] = v.z; tile[r][c4 + 3] = v.w;
    __syncthreads();
    ushort4 o;
    o.x = f2bu(tile[c4 + 0][r]); o.y = f2bu(tile[c4 + 1][r]);
    o.z = f2bu(tile[c4 + 2][r]); o.w = f2bu(tile[c4 + 3][r]);
    *(ushort4*)(dst + (size_t)(n0 + r) * K + k0 + c4) = o;
}

// ---------------------------------------------------------------- encoder stage 1 (8 rows/block, scalar-broadcast inputs)
__global__ __launch_bounds__(256) void enc1_kernel(
    const float* __restrict__ x, const float* __restrict__ pos,
    const float* __restrict__ w1, const float* __restrict__ b1,
    unsigned short* __restrict__ mid)
{
    int t = threadIdx.x;
    int row0 = blockIdx.x * 8;
    float w[6];
#pragma unroll
    for (int j = 0; j < 6; j++) w[j] = w1[j * 256 + t];
    float bias = b1[t];
#pragma unroll
    for (int rr = 0; rr < 8; rr++) {
        int row = row0 + rr;
        float acc = bias
            + x[row * 3 + 0] * w[0] + x[row * 3 + 1] * w[1] + x[row * 3 + 2] * w[2]
            + pos[row * 3 + 0] * w[3] + pos[row * 3 + 1] * w[4] + pos[row * 3 + 2] * w[5];
        mid[(size_t)row * 256 + t] = f2bu(fmaxf(acc, 0.f));
    }
}

// ---------------------------------------------------------------- bf16 MFMA GEMM, 128x64 tile (2x residency), XCD swizzle
template<int RELU>
__global__ __launch_bounds__(256) void gemm_bf16_n64_kernel(
    const unsigned short* __restrict__ A, const unsigned short* __restrict__ Bt,
    const float* __restrict__ bias, unsigned short* __restrict__ C,
    int M, int K, int Nc, int nx)
{
    __shared__ __align__(16) unsigned short As[128 * 32];   // 8 KB
    __shared__ __align__(16) unsigned short Bs[64 * 32];    // 4 KB
    const int tid = threadIdx.x;
    const int id = blockIdx.x;
    const int xcd = id & 7, slot = id >> 3;
    const int bm = ((slot / nx) * 8 + xcd) * 128;
    const int bn = (slot % nx) * 64;
    const int wave = tid >> 6, lane = tid & 63;
    const int wr = (wave >> 1) * 64, wc = (wave & 1) * 32;
    const int lm = lane & 15, lk = (lane >> 4) * 8;

    f32x4_t acc[4][2];
#pragma unroll
    for (int i = 0; i < 4; i++)
#pragma unroll
        for (int j = 0; j < 2; j++)
            acc[i][j] = (f32x4_t){0.f, 0.f, 0.f, 0.f};

    for (int k0 = 0; k0 < K; k0 += 32) {
#pragma unroll
        for (int it = 0; it < 2; ++it) {
            int t = tid + it * 256;
            const unsigned short* gp = A + (size_t)(bm + (t >> 2)) * K + k0 + (t & 3) * 8;
            __builtin_amdgcn_global_load_lds((gas_t)(const char*)gp,
                (las_t)((char*)As + t * 16), 16, 0, 0);
        }
        {
            int t = tid;
            const unsigned short* gp = Bt + (size_t)(bn + (t >> 2)) * K + k0 + (t & 3) * 8;
            __builtin_amdgcn_global_load_lds((gas_t)(const char*)gp,
                (las_t)((char*)Bs + t * 16), 16, 0, 0);
        }
        __syncthreads();
        bf16x8_t af[4], bfr[2];
#pragma unroll
        for (int i = 0; i < 4; i++)
            af[i] = *(const bf16x8_t*)(As + (size_t)(wr + 16 * i + lm) * 32 + lk);
#pragma unroll
        for (int j = 0; j < 2; j++)
            bfr[j] = *(const bf16x8_t*)(Bs + (size_t)(wc + 16 * j + lm) * 32 + lk);
#pragma unroll
        for (int i = 0; i < 4; i++)
#pragma unroll
            for (int j = 0; j < 2; j++)
                acc[i][j] = __builtin_amdgcn_mfma_f32_16x16x32_bf16(af[i], bfr[j], acc[i][j], 0, 0, 0);
        __syncthreads();
    }

    const int col_l = lane & 15;
    const int row_q = (lane >> 4) * 4;
#pragma unroll
    for (int i = 0; i < 4; i++) {
#pragma unroll
        for (int j = 0; j < 2; j++) {
            int gn = bn + wc + 16 * j + col_l;
            float bsv = bias[gn];
            int gm0 = bm + wr + 16 * i + row_q;
#pragma unroll
            for (int r = 0; r < 4; r++) {
                float v = acc[i][j][r] + bsv;
                if (RELU) v = fmaxf(v, 0.f);
                C[(size_t)(gm0 + r) * Nc + gn] = f2bu(v);
            }
        }
    }
}

// ---------------------------------------------------------------- fused QKV GEMM, 128x64 tile (nx=24 -> 12 blocks/CU), XCD swizzle
__global__ __launch_bounds__(256) void gemm_qkv_kernel(
    const unsigned short* __restrict__ A, const unsigned short* __restrict__ Bt,
    const float* __restrict__ bq, const float* __restrict__ bk, const float* __restrict__ bv,
    unsigned short* __restrict__ Q, unsigned short* __restrict__ Kk,
    unsigned short* __restrict__ vT)
{
    __shared__ __align__(16) unsigned short As[128 * 32];
    __shared__ __align__(16) unsigned short Bs[64 * 32];
    const int tid = threadIdx.x;
    const int id = blockIdx.x;
    const int xcd = id & 7, slot = id >> 3;
    const int bm = ((slot / 24) * 8 + xcd) * 128;
    const int bn = (slot % 24) * 64;
    const int wave = tid >> 6, lane = tid & 63;
    const int wr = (wave >> 1) * 64, wc = (wave & 1) * 32;
    const int lm = lane & 15, lk = (lane >> 4) * 8;
    const int K = DMODEL;

    f32x4_t acc[4][2];
#pragma unroll
    for (int i = 0; i < 4; i++)
#pragma unroll
        for (int j = 0; j < 2; j++)
            acc[i][j] = (f32x4_t){0.f, 0.f, 0.f, 0.f};

    for (int k0 = 0; k0 < K; k0 += 32) {
#pragma unroll
        for (int it = 0; it < 2; ++it) {
            int t = tid + it * 256;
            const unsigned short* gp = A + (size_t)(bm + (t >> 2)) * K + k0 + (t & 3) * 8;
            __builtin_amdgcn_global_load_lds((gas_t)(const char*)gp,
                (las_t)((char*)As + t * 16), 16, 0, 0);
        }
        {
            int t = tid;
            const unsigned short* gp = Bt + (size_t)(bn + (t >> 2)) * K + k0 + (t & 3) * 8;
            __builtin_amdgcn_global_load_lds((gas_t)(const char*)gp,
                (las_t)((char*)Bs + t * 16), 16, 0, 0);
        }
        __syncthreads();
        bf16x8_t af[4], bfr[2];
#pragma unroll
        for (int i = 0; i < 4; i++)
            af[i] = *(const bf16x8_t*)(As + (size_t)(wr + 16 * i + lm) * 32 + lk);
#pragma unroll
        for (int j = 0; j < 2; j++)
            bfr[j] = *(const bf16x8_t*)(Bs + (size_t)(wc + 16 * j + lm) * 32 + lk);
#pragma unroll
        for (int i = 0; i < 4; i++)
#pragma unroll
            for (int j = 0; j < 2; j++)
                acc[i][j] = __builtin_amdgcn_mfma_f32_16x16x32_bf16(af[i], bfr[j], acc[i][j], 0, 0, 0);
        __syncthreads();
    }

    // 64-aligned column tile: section (q/k/v) and head are uniform per block
    const int sect = bn >> 9;
    const float* bias = (sect == 0) ? bq : (sect == 1) ? bk : bv;
    unsigned short* rowout = (sect == 0) ? Q : Kk;
    const int cb = bn & 511;
    const int col_l = lane & 15;
    const int row_q = (lane >> 4) * 4;
#pragma unroll
    for (int i = 0; i < 4; i++) {
#pragma unroll
        for (int j = 0; j < 2; j++) {
            int cn = cb + wc + 16 * j + col_l;
            float bsv = bias[cn];
            int gm0 = bm + wr + 16 * i + row_q;
            if (sect < 2) {
#pragma unroll
                for (int r = 0; r < 4; r++)
                    rowout[(size_t)(gm0 + r) * DMODEL + cn] = f2bu(acc[i][j][r] + bsv);
            } else {
                int bb_ = gm0 >> 10, ss = gm0 & 1023;
                int hh_ = cn >> 6, dd = cn & 63;
                u16x4 o4;
#pragma unroll
                for (int r = 0; r < 4; r++) o4[r] = f2bu(acc[i][j][r] + bsv);
                *(u16x4*)(vT + (((size_t)(bb_ * NHEAD + hh_) * HDIM + dd) * SEQ + ss)) = o4;
            }
        }
    }
}

// ---------------------------------------------------------------- fused FAVOR K-features + kv accumulate (v5: 4x256-token chunks, bf16 partials)
__global__ __launch_bounds__(256) void favor_k_kv_kernel(
    const unsigned short* __restrict__ Kx,   // [N,DM] bf16
    const unsigned short* __restrict__ vT,   // [BH,64,1024] bf16
    const unsigned short* __restrict__ omT,  // [128][64] bf16 pre-scaled
    unsigned short* __restrict__ kvpart,     // [4][BH][64][256] bf16
    float* __restrict__ kspart)              // [4][BH][256] f32
{
    const int bid = blockIdx.x;
    const int xcd = bid & 7, slot = bid >> 3;    // 512 blocks -> slot 0..63
    const int chunk = slot & 3;
    const int bh = (slot >> 2) * 8 + xcd;
    const int b = bh >> 3, h = bh & 7;
    const int tid = threadIdx.x;
    const int wave = tid >> 6, lane = tid & 63;
    const int lm = lane & 15, q = lane >> 4, lk = q * 8;
    const int quad4 = q * 4;
    const int wr = wave * 64;       // f-rows for kv MFMA
    const int m0 = wave * 16;       // tokens for u MFMA

    __shared__ __align__(16) unsigned short phiT[256 * 72];  // 36 KB [f][m]

    f32x4_t acc_kv[4][4];
#pragma unroll
    for (int i = 0; i < 4; i++)
#pragma unroll
        for (int j = 0; j < 4; j++)
            acc_kv[i][j] = (f32x4_t){0.f, 0.f, 0.f, 0.f};
    float ks_acc = 0.f;

    const unsigned short* vbase = vT + (size_t)bh * HDIM * SEQ;

    for (int st = 0; st < 4; ++st) {
        int s0 = chunk * 256 + st * 64;
        // A-frags from global
        const unsigned short* krow = Kx + (size_t)(b * SEQ + s0 + m0 + lm) * DMODEL + h * HDIM;
        u16x8 xu0 = *(const u16x8*)(krow + lk);
        u16x8 xu1 = *(const u16x8*)(krow + 32 + lk);
        float p = 0.f;
#pragma unroll
        for (int e = 0; e < 8; e++) {
            float a = b2f(xu0[e]), c = b2f(xu1[e]);
            p += a * a + c * c;
        }
        p += __shfl_xor(p, 16, 64);
        p += __shfl_xor(p, 32, 64);
        float hred = 0.5f * SCALE2 * p;      // h for token m0+lm, all lanes
        float hr[4];
#pragma unroll
        for (int r = 0; r < 4; r++) hr[r] = __shfl(hred, quad4 + r, 64);
        // u MFMA
        f32x4_t acc[8];
#pragma unroll
        for (int j = 0; j < 8; j++) acc[j] = (f32x4_t){0.f, 0.f, 0.f, 0.f};
        bf16x8_t af0 = u2b8(xu0), af1 = u2b8(xu1);
#pragma unroll
        for (int j = 0; j < 8; j++) {
            bf16x8_t b0 = *(const bf16x8_t*)(omT + (size_t)(j * 16 + lm) * 64 + lk);
            acc[j] = __builtin_amdgcn_mfma_f32_16x16x32_bf16(af0, b0, acc[j], 0, 0, 0);
            bf16x8_t b1 = *(const bf16x8_t*)(omT + (size_t)(j * 16 + lm) * 64 + 32 + lk);
            acc[j] = __builtin_amdgcn_mfma_f32_16x16x32_bf16(af1, b1, acc[j], 0, 0, 0);
        }
        __syncthreads();   // prior phiT readers done before overwrite
        // epilogue: phi -> phiT [f][m]
#pragma unroll
        for (int j = 0; j < 8; j++) {
            int f = j * 16 + lm;
#pragma unroll
            for (int r = 0; r < 4; r++) {
                int m = m0 + quad4 + r;
                float u = acc[j][r];
                phiT[f * 72 + m]         = f2bu(__expf(u - hr[r]) * FSCALE);
                phiT[(f + 128) * 72 + m] = f2bu(__expf(-u - hr[r]) * FSCALE);
            }
        }
        __syncthreads();   // phiT ready
        // ksum partial: thread owns feature f = tid
        {
            const unsigned short* row = &phiT[tid * 72];
#pragma unroll
            for (int mm = 0; mm < 64; mm += 8) {
                u16x8 v = *(const u16x8*)(row + mm);
#pragma unroll
                for (int e = 0; e < 8; e++) ks_acc += b2f(v[e]);
            }
        }
        // kv MFMA: A = phiT [f][s], B = vT [d][s] (global)
#pragma unroll
        for (int ks = 0; ks < 2; ks++) {
            bf16x8_t af[4], bfr[4];
#pragma unroll
            for (int i = 0; i < 4; i++)
                af[i] = *(const bf16x8_t*)&phiT[(wr + 16 * i + lm) * 72 + ks * 32 + lk];
#pragma unroll
            for (int j = 0; j < 4; j++)
                bfr[j] = *(const bf16x8_t*)(vbase + (size_t)(16 * j + lm) * SEQ + s0 + ks * 32 + lk);
#pragma unroll
            for (int i = 0; i < 4; i++)
#pragma unroll
                for (int j = 0; j < 4; j++)
                    acc_kv[i][j] = __builtin_amdgcn_mfma_f32_16x16x32_bf16(af[i], bfr[j], acc_kv[i][j], 0, 0, 0);
        }
    }

    // write kv partial (bf16): layout [chunk][bh][d][f]
    unsigned short* kp = kvpart + ((size_t)chunk * BH_TOT + bh) * HDIM * FDIM;
#pragma unroll
    for (int i = 0; i < 4; i++) {
#pragma unroll
        for (int j = 0; j < 4; j++) {
            int d = 16 * j + lm;
            int f0 = wr + 16 * i + quad4;
            u16x4 o4;
#pragma unroll
            for (int r = 0; r < 4; r++) o4[r] = f2bu(acc_kv[i][j][r]);
            *(u16x4*)(kp + (size_t)d * FDIM + f0) = o4;
        }
    }
    kspart[(size_t)chunk * (BH_TOT * FDIM) + (size_t)bh * FDIM + tid] = ks_acc;
}

// ---------------------------------------------------------------- reduce 4 bf16 kv partials -> bf16 kvT; 4 f32 ks partials -> f32 ksum
__global__ __launch_bounds__(256) void reduce_kv_kernel(
    const unsigned short* __restrict__ in_kv, const float* __restrict__ in_ks,
    unsigned short* __restrict__ out_kv, float* __restrict__ out_ks)
{
    const int NKV = BH_TOT * HDIM * FDIM;   // 2097152
    const int NKS = BH_TOT * FDIM;          // 32768
    int blk = blockIdx.x;
    if (blk < 1024) {
        size_t base = ((size_t)blk * 256 + threadIdx.x) * 8;
        u16x8 v0 = *(const u16x8*)(in_kv + base);
        u16x8 v1 = *(const u16x8*)(in_kv + base + NKV);
        u16x8 v2 = *(const u16x8*)(in_kv + base + 2 * (size_t)NKV);
        u16x8 v3 = *(const u16x8*)(in_kv + base + 3 * (size_t)NKV);
        u16x8 o;
#pragma unroll
        for (int e = 0; e < 8; e++)
            o[e] = f2bu(b2f(v0[e]) + b2f(v1[e]) + b2f(v2[e]) + b2f(v3[e]));
        *(u16x8*)(out_kv + base) = o;
    } else {
        size_t j = ((size_t)(blk - 1024) * 256 + threadIdx.x) * 4;
        float4 a0 = *(const float4*)(in_ks + j);
        float4 a1 = *(const float4*)(in_ks + j + NKS);
        float4 a2 = *(const float4*)(in_ks + j + 2 * (size_t)NKS);
        float4 a3 = *(const float4*)(in_ks + j + 3 * (size_t)NKS);
        float4 o = make_float4(a0.x + a1.x + a2.x + a3.x, a0.y + a1.y + a2.y + a3.y,
                               a0.z + a1.z + a2.z + a3.z, a0.w + a1.w + a2.w + a3.w);
        *(float4*)(out_ks + j) = o;
    }
}

// ---------------------------------------------------------------- fused FAVOR Q-features + attention (v8: shared kss, zero barriers)
__global__ __launch_bounds__(256) void favor_q_attn_kernel(
    const unsigned short* __restrict__ Qx,   // [N,DM] bf16
    const unsigned short* __restrict__ omT,  // [128][64] bf16 pre-scaled
    const unsigned short* __restrict__ kvT,  // [BH,64,256] bf16
    const float* __restrict__ ksum,          // [BH,256] f32
    unsigned short* __restrict__ outX)       // [N,DM] bf16
{
    const int bid = blockIdx.x;
    const int xcd = bid & 7, slot = bid >> 3;   // 2048 blocks -> slot 0..255
    const int sc = slot & 15;
    const int bh = (slot >> 4) * 8 + xcd;       // all 16 tiles of a bh share one XCD
    const int b = bh >> 3, h = bh & 7;
    const int s0 = sc * 64;
    const int tid = threadIdx.x;
    const int wave = tid >> 6, lane = tid & 63;
    const int lm = lane & 15, q = lane >> 4, lk = q * 8;
    const int quad4 = q * 4;
    const int m0 = wave * 16;

    __shared__ __align__(16) unsigned short phis[4][16 * 136]; // 17.4 KB per-wave slices
    __shared__ __align__(16) float kss[256];                   // 1 KB shared (identical writes)

    // every wave writes the full copy -> no cross-wave dependency, no barrier
    *(float4*)&kss[lane * 4] = *(const float4*)(ksum + (size_t)bh * FDIM + lane * 4);

    // Q A-frags from global
    const unsigned short* qrow = Qx + (size_t)(b * SEQ + s0 + m0 + lm) * DMODEL + h * HDIM;
    u16x8 xu0 = *(const u16x8*)(qrow + lk);
    u16x8 xu1 = *(const u16x8*)(qrow + 32 + lk);
    float p = 0.f;
#pragma unroll
    for (int e = 0; e < 8; e++) {
        float a = b2f(xu0[e]), c = b2f(xu1[e]);
        p += a * a + c * c;
    }
    p += __shfl_xor(p, 16, 64);
    p += __shfl_xor(p, 32, 64);
    float hred = 0.5f * SCALE2 * p;          // h for token m0+lm
    float hr[4];
#pragma unroll
    for (int r = 0; r < 4; r++) hr[r] = __shfl(hred, quad4 + r, 64);

    // u MFMA
    f32x4_t acc[8];
#pragma unroll
    for (int j = 0; j < 8; j++) acc[j] = (f32x4_t){0.f, 0.f, 0.f, 0.f};
    bf16x8_t af0 = u2b8(xu0), af1 = u2b8(xu1);
#pragma unroll
    for (int j = 0; j < 8; j++) {
        bf16x8_t b0 = *(const bf16x8_t*)(omT + (size_t)(j * 16 + lm) * 64 + lk);
        acc[j] = __builtin_amdgcn_mfma_f32_16x16x32_bf16(af0, b0, acc[j], 0, 0, 0);
        bf16x8_t b1 = *(const bf16x8_t*)(omT + (size_t)(j * 16 + lm) * 64 + 32 + lk);
        acc[j] = __builtin_amdgcn_mfma_f32_16x16x32_bf16(af1, b1, acc[j], 0, 0, 0);
    }

    // pass-1 epilogue: phi+ -> own LDS slice; z accumulated in registers
    unsigned short* ph = phis[wave];
    float zp[4] = {0.f, 0.f, 0.f, 0.f};
#pragma unroll
    for (int j = 0; j < 8; j++) {
        int f = j * 16 + lm;
        float ksp = kss[f], ksm = kss[128 + f];
#pragma unroll
        for (int r = 0; r < 4; r++) {
            float u = acc[j][r];
            float pp = __expf(u - hr[r]) * FSCALE;
            float pm = __expf(-u - hr[r]) * FSCALE;
            ph[(quad4 + r) * 136 + f] = f2bu(pp);
            zp[r] += pp * ksp + pm * ksm;
        }
    }
#pragma unroll
    for (int off = 1; off < 16; off <<= 1) {
        zp[0] += __shfl_xor(zp[0], off, 64);
        zp[1] += __shfl_xor(zp[1], off, 64);
        zp[2] += __shfl_xor(zp[2], off, 64);
        zp[3] += __shfl_xor(zp[3], off, 64);
    }
    float zinv[4];
#pragma unroll
    for (int r = 0; r < 4; r++) zinv[r] = 1.f / (zp[r] + 1e-6f);

    const unsigned short* kvbase = kvT + (size_t)bh * HDIM * FDIM;
    f32x4_t acc_o[4];
#pragma unroll
    for (int j = 0; j < 4; j++) acc_o[j] = (f32x4_t){0.f, 0.f, 0.f, 0.f};
    // pass 1: features [0,128)
#pragma unroll
    for (int k0 = 0; k0 < 128; k0 += 32) {
        bf16x8_t af = *(const bf16x8_t*)&ph[lm * 136 + k0 + lk];
#pragma unroll
        for (int j = 0; j < 4; j++) {
            bf16x8_t bfr = *(const bf16x8_t*)(kvbase + (size_t)(16 * j + lm) * FDIM + k0 + lk);
            acc_o[j] = __builtin_amdgcn_mfma_f32_16x16x32_bf16(af, bfr, acc_o[j], 0, 0, 0);
        }
    }
    // pass-2 epilogue: overwrite own slice with phi- (recompute exp; keeps VGPR <= 64)
#pragma unroll
    for (int j = 0; j < 8; j++) {
        int f = j * 16 + lm;
#pragma unroll
        for (int r = 0; r < 4; r++)
            ph[(quad4 + r) * 136 + f] = f2bu(__expf(-acc[j][r] - hr[r]) * FSCALE);
    }
    // pass 2: features [128,256)
#pragma unroll
    for (int k0 = 0; k0 < 128; k0 += 32) {
        bf16x8_t af = *(const bf16x8_t*)&ph[lm * 136 + k0 + lk];
#pragma unroll
        for (int j = 0; j < 4; j++) {
            bf16x8_t bfr = *(const bf16x8_t*)(kvbase + (size_t)(16 * j + lm) * FDIM + 128 + k0 + lk);
            acc_o[j] = __builtin_amdgcn_mfma_f32_16x16x32_bf16(af, bfr, acc_o[j], 0, 0, 0);
        }
    }
    // epilogue: scale by z, store
#pragma unroll
    for (int r = 0; r < 4; r++) {
        int s = s0 + m0 + quad4 + r;
#pragma unroll
        for (int j = 0; j < 4; j++) {
            int d = 16 * j + lm;
            outX[(size_t)(b * SEQ + s) * DMODEL + h * HDIM + d] = f2bu(acc_o[j][r] * zinv[r]);
        }
    }
}

// ---------------------------------------------------------------- residual + LayerNorm (wave-per-row, zero barriers, zero LDS)
template<int HAS_RES>
__global__ __launch_bounds__(512) void add_ln_kernel(
    const unsigned short* __restrict__ res16, const unsigned short* __restrict__ tin16,
    const float* __restrict__ g, const float* __restrict__ bb,
    unsigned short* __restrict__ out16)
{
    int wave = threadIdx.x >> 6, lane = threadIdx.x & 63;
    int row = blockIdx.x * 8 + wave;
    size_t base = (size_t)row * DMODEL + lane * 8;
    u16x8 tv = *(const u16x8*)(tin16 + base);
    float v[8];
    float s1 = 0.f, s2 = 0.f;
    if (HAS_RES) {
        u16x8 rv = *(const u16x8*)(res16 + base);
#pragma unroll
        for (int e = 0; e < 8; e++) v[e] = b2f(tv[e]) + b2f(rv[e]);
    } else {
#pragma unroll
        for (int e = 0; e < 8; e++) v[e] = b2f(tv[e]);
    }
#pragma unroll
    for (int e = 0; e < 8; e++) { s1 += v[e]; s2 += v[e] * v[e]; }
#pragma unroll
    for (int off = 1; off < 64; off <<= 1) {
        s1 += __shfl_xor(s1, off, 64);
        s2 += __shfl_xor(s2, off, 64);
    }
    float m = s1 * (1.f / DMODEL);
    float var = s2 * (1.f / DMODEL) - m * m;
    float r = rsqrtf(var + 1e-5f);
    float4 g0 = *(const float4*)(g + lane * 8);
    float4 g1 = *(const float4*)(g + lane * 8 + 4);
    float4 b0 = *(const float4*)(bb + lane * 8);
    float4 b1 = *(const float4*)(bb + lane * 8 + 4);
    float gg[8] = {g0.x, g0.y, g0.z, g0.w, g1.x, g1.y, g1.z, g1.w};
    float bbv[8] = {b0.x, b0.y, b0.z, b0.w, b1.x, b1.y, b1.z, b1.w};
    u16x8 o;
#pragma unroll
    for (int e = 0; e < 8; e++)
        o[e] = f2bu((v[e] - m) * r * gg[e] + bbv[e]);
    *(u16x8*)(out16 + base) = o;
}

// ---------------------------------------------------------------- pool stage 1
__global__ __launch_bounds__(256) void pool_part_kernel(
    const unsigned short* __restrict__ h16, float* __restrict__ pbuf)
{
    int blk = blockIdx.x;
    int b = blk >> 4, ch = blk & 15;
    int t = threadIdx.x;
    int d0 = t * 2;
    float a0 = 0.f, a1 = 0.f;
    const unsigned short* base = h16 + ((size_t)(b * SEQ + ch * 64) * DMODEL) + d0;
#pragma unroll 4
    for (int s = 0; s < 64; s++) {
        ushort2 v = *(const ushort2*)(base + (size_t)s * DMODEL);
        a0 += b2f(v.x); a1 += b2f(v.y);
    }
    *(float2*)(pbuf + (size_t)blk * DMODEL + d0) = make_float2(a0, a1);
}

// ---------------------------------------------------------------- pool stage 2 + classify
__global__ __launch_bounds__(512) void cls_kernel(
    const float* __restrict__ pbuf, const float* __restrict__ cls_w,
    const float* __restrict__ cls_b, float* __restrict__ out)
{
    int b = blockIdx.x, t = threadIdx.x;
    float s = 0.f;
#pragma unroll
    for (int c = 0; c < 16; c++) s += pbuf[(size_t)(b * 16 + c) * DMODEL + t];
    __shared__ float pooled[DMODEL];
    pooled[t] = s * (1.f / SEQ);
    __syncthreads();
    if (t < 16) {
        float acc = cls_b[t];
        for (int c = 0; c < DMODEL; c++) acc += pooled[c] * cls_w[c * 16 + t];
        out[b * 16 + t] = acc;
    }
}

// ----------------------------------------------------------------
extern "C" void kernel_launch(void* const* d_in, const int* in_sizes, int n_in,
                              void* d_out, int out_size, void* d_ws, size_t ws_size,
                              hipStream_t stream)
{
    const float* x      = (const float*)d_in[0];
    const float* pos    = (const float*)d_in[1];
    const float* enc_w1 = (const float*)d_in[2];
    const float* enc_b1 = (const float*)d_in[3];
    const float* enc_w2 = (const float*)d_in[4];
    const float* enc_b2 = (const float*)d_in[5];
    const float* enc_g  = (const float*)d_in[6];
    const float* enc_bb = (const float*)d_in[7];
    const float* wq = (const float*)d_in[8];
    const float* bq = (const float*)d_in[9];
    const float* wk = (const float*)d_in[10];
    const float* bk = (const float*)d_in[11];
    const float* wv = (const float*)d_in[12];
    const float* bv = (const float*)d_in[13];
    const float* wo = (const float*)d_in[14];
    const float* bo = (const float*)d_in[15];
    const float* ln1_g = (const float*)d_in[16];
    const float* ln1_b = (const float*)d_in[17];
    const float* w1 = (const float*)d_in[18];
    const float* b1 = (const float*)d_in[19];
    const float* w2 = (const float*)d_in[20];
    const float* b2 = (const float*)d_in[21];
    const float* ln2_g = (const float*)d_in[22];
    const float* ln2_b = (const float*)d_in[23];
    const float* omega = (const float*)d_in[24];
    const float* cls_w = (const float*)d_in[25];
    const float* cls_b = (const float*)d_in[26];
    float* out = (float*)d_out;

    const int N = NTOK;
    const int BH = BH_TOT;

    char* p = (char*)d_ws;
    unsigned short* qb16 = (unsigned short*)p; p += (size_t)N * DMODEL * 2;   // 16MB
    unsigned short* kb16 = (unsigned short*)p; p += (size_t)N * DMODEL * 2;   // 16MB
    unsigned short* vT16 = (unsigned short*)p; p += (size_t)N * DMODEL * 2;   // 16MB
    unsigned short* h16  = (unsigned short*)p; p += (size_t)N * DMODEL * 2;   // 16MB
    unsigned short* mid16 = (unsigned short*)p; p += (size_t)N * 1024 * 2;    // 32MB
    unsigned short* attn16 = (unsigned short*)p; p += (size_t)N * DMODEL * 2; // 16MB
    unsigned short* kvpart = (unsigned short*)p; p += (size_t)4 * BH * HDIM * FDIM * 2; // 16.8MB
    float* kspart = (float*)p;                 p += (size_t)4 * BH * FDIM * 4;          // 512KB
    unsigned short* kvT16 = (unsigned short*)p; p += (size_t)BH * HDIM * FDIM * 2;      // 4MB
    float* ksb = (float*)p;                    p += (size_t)BH * FDIM * 4;    // 128KB
    float* pbuf = (float*)p;                   p += (size_t)BATCH * 16 * DMODEL * 4;    // 512KB
    unsigned short* enc_w2t = (unsigned short*)p; p += (size_t)256 * 512 * 2;
    unsigned short* wqkvt = (unsigned short*)p; p += (size_t)4 * 1536 * 512 * 2;  // 6MB
    unsigned short* wot = (unsigned short*)p;  p += (size_t)4 * 512 * 512 * 2;
    unsigned short* w1t = (unsigned short*)p;  p += (size_t)4 * 512 * 1024 * 2;
    unsigned short* w2t = (unsigned short*)p;  p += (size_t)4 * 1024 * 512 * 2;
    unsigned short* omT = (unsigned short*)p;  p += (size_t)4 * 128 * 64 * 2;

    // ---- all weight conversion in one dispatch ----
    convT_all_kernel<<<8448, 256, 0, stream>>>(
        enc_w2, wq, wk, wv, wo, w1, w2, omega,
        enc_w2t, wqkvt, wot, w1t, w2t, omT);

    // ---- encoder ----
    enc1_kernel<<<N / 8, 256, 0, stream>>>(x, pos, enc_w1, enc_b1, mid16);
    gemm_bf16_n64_kernel<0><<<8 * 128, 256, 0, stream>>>(mid16, enc_w2t, enc_b2, qb16, N, 256, 512, 8);
    add_ln_kernel<0><<<N / 8, 512, 0, stream>>>(nullptr, qb16, enc_g, enc_bb, h16);

    // ---- layers ----
    for (int l = 0; l < 4; l++) {
        const unsigned short* omT_l = omT + (size_t)l * 8192;
        gemm_qkv_kernel<<<24 * 128, 256, 0, stream>>>(
            h16, wqkvt + (size_t)l * 786432,
            bq + l * DMODEL, bk + l * DMODEL, bv + l * DMODEL,
            qb16, kb16, vT16);
        favor_k_kv_kernel<<<BH * 4, 256, 0, stream>>>(kb16, vT16, omT_l, kvpart, kspart);
        reduce_kv_kernel<<<1056, 256, 0, stream>>>(kvpart, kspart, kvT16, ksb);
        favor_q_attn_kernel<<<BH * 16, 256, 0, stream>>>(qb16, omT_l, kvT16, ksb, attn16);
        gemm_bf16_n64_kernel<0><<<8 * 128, 256, 0, stream>>>(attn16, wot + (size_t)l * 262144, bo + l * DMODEL, qb16, N, 512, 512, 8);
        add_ln_kernel<1><<<N / 8, 512, 0, stream>>>(h16, qb16, ln1_g + l * DMODEL, ln1_b + l * DMODEL, h16);
        gemm_bf16_n64_kernel<1><<<16 * 128, 256, 0, stream>>>(h16, w1t + (size_t)l * 524288, b1 + l * 1024, mid16, N, 512, 1024, 16);
        gemm_bf16_n64_kernel<0><<<8 * 128, 256, 0, stream>>>(mid16, w2t + (size_t)l * 524288, b2 + l * DMODEL, qb16, N, 1024, 512, 8);
        add_ln_kernel<1><<<N / 8, 512, 0, stream>>>(h16, qb16, ln2_g + l * DMODEL, ln2_b + l * DMODEL, h16);
    }

    // ---- pool + classify ----
    pool_part_kernel<<<BATCH * 16, 256, 0, stream>>>(h16, pbuf);
    cls_kernel<<<BATCH, 512, 0, stream>>>(pbuf, cls_w, cls_b, out);
}

// Round 16
// 1028.197 us; speedup vs baseline: 1.0241x; 1.0241x over previous
//
#include <hip/hip_runtime.h>
#include <hip/hip_bf16.h>
#include <math.h>

// Dims (fixed): B=16, S=1024, N=16384, DM=512, H=8, D=64, F=256, L=4
#define NTOK 16384
#define BATCH 16
#define SEQ 1024
#define DMODEL 512
#define NHEAD 8
#define HDIM 64
#define FDIM 256
#define BH_TOT 128
#define SCALE_QK 0.3535533905932738f   // 64^-0.25
#define SCALE2 0.125f                  // SCALE_QK^2
#define FSCALE 0.0625f                 // 256^-0.5

typedef __bf16 bf16x8_t __attribute__((ext_vector_type(8)));
typedef float f32x4_t  __attribute__((ext_vector_type(4)));
typedef unsigned short u16x8 __attribute__((ext_vector_type(8)));
typedef unsigned short u16x4 __attribute__((ext_vector_type(4)));
typedef const __attribute__((address_space(1))) char* gas_t;
typedef __attribute__((address_space(3))) char* las_t;

__device__ __forceinline__ float b2f(unsigned short u) {
    union { unsigned int i; float f; } c; c.i = ((unsigned int)u) << 16; return c.f;
}
__device__ __forceinline__ unsigned short f2bu(float f) {
    __hip_bfloat16 h = __float2bfloat16(f);
    return *(unsigned short*)&h;
}
__device__ __forceinline__ bf16x8_t u2b8(u16x8 u) {
    union { u16x8 a; bf16x8_t b; } c; c.a = u; return c.b;
}

// ---------------------------------------------------------------- ALL weight conversions in ONE kernel (7 convT segments + omega)
__global__ __launch_bounds__(256) void convT_all_kernel(
    const float* __restrict__ enc_w2, const float* __restrict__ wq,
    const float* __restrict__ wk, const float* __restrict__ wv,
    const float* __restrict__ wo, const float* __restrict__ w1,
    const float* __restrict__ w2, const float* __restrict__ omega,
    unsigned short* __restrict__ enc_w2t, unsigned short* __restrict__ wqkvt,
    unsigned short* __restrict__ wot, unsigned short* __restrict__ w1t,
    unsigned short* __restrict__ w2t, unsigned short* __restrict__ omT)
{
    int blk = blockIdx.x;
    int t = threadIdx.x;
    if (blk >= 8320) {   // omega: [L][64][128] f32 -> [L][128][64] bf16 * SCALE_QK
        int i = (blk - 8320) * 256 + t;
        int l = i >> 13, rem = i & 8191;
        int f = rem >> 6, d = rem & 63;
        omT[(size_t)l * 8192 + f * 64 + d] =
            f2bu(omega[(size_t)l * 8192 + d * 128 + f] * SCALE_QK);
        return;
    }
    const float* src; unsigned short* dst;
    int K, N, tpl_sh, nx_sh; size_t in_ls, out_ls; int rem;
    if (blk < 128)       { src = enc_w2; dst = enc_w2t;        K = 256;  N = 512;  tpl_sh = 7; nx_sh = 4; in_ls = 0;      out_ls = 0;      rem = blk; }
    else if (blk < 1152) { src = wq;     dst = wqkvt;          K = 512;  N = 512;  tpl_sh = 8; nx_sh = 4; in_ls = 262144; out_ls = 786432; rem = blk - 128; }
    else if (blk < 2176) { src = wk;     dst = wqkvt + 262144; K = 512;  N = 512;  tpl_sh = 8; nx_sh = 4; in_ls = 262144; out_ls = 786432; rem = blk - 1152; }
    else if (blk < 3200) { src = wv;     dst = wqkvt + 524288; K = 512;  N = 512;  tpl_sh = 8; nx_sh = 4; in_ls = 262144; out_ls = 786432; rem = blk - 2176; }
    else if (blk < 4224) { src = wo;     dst = wot;            K = 512;  N = 512;  tpl_sh = 8; nx_sh = 4; in_ls = 262144; out_ls = 262144; rem = blk - 3200; }
    else if (blk < 6272) { src = w1;     dst = w1t;            K = 512;  N = 1024; tpl_sh = 9; nx_sh = 5; in_ls = 524288; out_ls = 524288; rem = blk - 4224; }
    else                 { src = w2;     dst = w2t;            K = 1024; N = 512;  tpl_sh = 9; nx_sh = 4; in_ls = 524288; out_ls = 524288; rem = blk - 6272; }
    int l = rem >> tpl_sh;
    int tt = rem & ((1 << tpl_sh) - 1);
    int ty = tt >> nx_sh, txi = tt & ((1 << nx_sh) - 1);
    src += (size_t)l * in_ls;
    dst += (size_t)l * out_ls;
    int k0 = ty * 32, n0 = txi * 32;

    __shared__ float tile[32][33];
    int r = t >> 3, c4 = (t & 7) * 4;
    float4 v = *(const float4*)(src + (size_t)(k0 + r) * N + n0 + c4);
    tile[r][c4 + 0] = v.x; tile[r][c4 + 1] = v.y;
    tile[r][c4 + 2] = v.z; tile[r][c4 + 3] = v.w;
    __syncthreads();
    ushort4 o;
    o.x = f2bu(tile[c4 + 0][r]); o.y = f2bu(tile[c4 + 1][r]);
    o.z = f2bu(tile[c4 + 2][r]); o.w = f2bu(tile[c4 + 3][r]);
    *(ushort4*)(dst + (size_t)(n0 + r) * K + k0 + c4) = o;
}

// ---------------------------------------------------------------- encoder stage 1 (8 rows/block, scalar-broadcast inputs)
__global__ __launch_bounds__(256) void enc1_kernel(
    const float* __restrict__ x, const float* __restrict__ pos,
    const float* __restrict__ w1, const float* __restrict__ b1,
    unsigned short* __restrict__ mid)
{
    int t = threadIdx.x;
    int row0 = blockIdx.x * 8;
    float w[6];
#pragma unroll
    for (int j = 0; j < 6; j++) w[j] = w1[j * 256 + t];
    float bias = b1[t];
#pragma unroll
    for (int rr = 0; rr < 8; rr++) {
        int row = row0 + rr;
        float acc = bias
            + x[row * 3 + 0] * w[0] + x[row * 3 + 1] * w[1] + x[row * 3 + 2] * w[2]
            + pos[row * 3 + 0] * w[3] + pos[row * 3 + 1] * w[4] + pos[row * 3 + 2] * w[5];
        mid[(size_t)row * 256 + t] = f2bu(fmaxf(acc, 0.f));
    }
}

// ---------------------------------------------------------------- bf16 MFMA GEMM, 128x64 tile (2x residency), XCD swizzle
template<int RELU>
__global__ __launch_bounds__(256) void gemm_bf16_n64_kernel(
    const unsigned short* __restrict__ A, const unsigned short* __restrict__ Bt,
    const float* __restrict__ bias, unsigned short* __restrict__ C,
    int M, int K, int Nc, int nx)
{
    __shared__ __align__(16) unsigned short As[128 * 32];   // 8 KB
    __shared__ __align__(16) unsigned short Bs[64 * 32];    // 4 KB
    const int tid = threadIdx.x;
    const int id = blockIdx.x;
    const int xcd = id & 7, slot = id >> 3;
    const int bm = ((slot / nx) * 8 + xcd) * 128;
    const int bn = (slot % nx) * 64;
    const int wave = tid >> 6, lane = tid & 63;
    const int wr = (wave >> 1) * 64, wc = (wave & 1) * 32;
    const int lm = lane & 15, lk = (lane >> 4) * 8;

    f32x4_t acc[4][2];
#pragma unroll
    for (int i = 0; i < 4; i++)
#pragma unroll
        for (int j = 0; j < 2; j++)
            acc[i][j] = (f32x4_t){0.f, 0.f, 0.f, 0.f};

    for (int k0 = 0; k0 < K; k0 += 32) {
#pragma unroll
        for (int it = 0; it < 2; ++it) {
            int t = tid + it * 256;
            const unsigned short* gp = A + (size_t)(bm + (t >> 2)) * K + k0 + (t & 3) * 8;
            __builtin_amdgcn_global_load_lds((gas_t)(const char*)gp,
                (las_t)((char*)As + t * 16), 16, 0, 0);
        }
        {
            int t = tid;
            const unsigned short* gp = Bt + (size_t)(bn + (t >> 2)) * K + k0 + (t & 3) * 8;
            __builtin_amdgcn_global_load_lds((gas_t)(const char*)gp,
                (las_t)((char*)Bs + t * 16), 16, 0, 0);
        }
        __syncthreads();
        bf16x8_t af[4], bfr[2];
#pragma unroll
        for (int i = 0; i < 4; i++)
            af[i] = *(const bf16x8_t*)(As + (size_t)(wr + 16 * i + lm) * 32 + lk);
#pragma unroll
        for (int j = 0; j < 2; j++)
            bfr[j] = *(const bf16x8_t*)(Bs + (size_t)(wc + 16 * j + lm) * 32 + lk);
#pragma unroll
        for (int i = 0; i < 4; i++)
#pragma unroll
            for (int j = 0; j < 2; j++)
                acc[i][j] = __builtin_amdgcn_mfma_f32_16x16x32_bf16(af[i], bfr[j], acc[i][j], 0, 0, 0);
        __syncthreads();
    }

    const int col_l = lane & 15;
    const int row_q = (lane >> 4) * 4;
#pragma unroll
    for (int i = 0; i < 4; i++) {
#pragma unroll
        for (int j = 0; j < 2; j++) {
            int gn = bn + wc + 16 * j + col_l;
            float bsv = bias[gn];
            int gm0 = bm + wr + 16 * i + row_q;
#pragma unroll
            for (int r = 0; r < 4; r++) {
                float v = acc[i][j][r] + bsv;
                if (RELU) v = fmaxf(v, 0.f);
                C[(size_t)(gm0 + r) * Nc + gn] = f2bu(v);
            }
        }
    }
}

// ---------------------------------------------------------------- fused QKV GEMM (128x128 tile, XCD swizzle, nx=12) — R14-measured best
__global__ __launch_bounds__(256) void gemm_qkv_kernel(
    const unsigned short* __restrict__ A, const unsigned short* __restrict__ Bt,
    const float* __restrict__ bq, const float* __restrict__ bk, const float* __restrict__ bv,
    unsigned short* __restrict__ Q, unsigned short* __restrict__ Kk,
    unsigned short* __restrict__ vT)
{
    __shared__ __align__(16) unsigned short As[128 * 32];
    __shared__ __align__(16) unsigned short Bs[128 * 32];
    const int tid = threadIdx.x;
    const int id = blockIdx.x;
    const int xcd = id & 7, slot = id >> 3;
    const int bm = ((slot / 12) * 8 + xcd) * 128;
    const int bn = (slot % 12) * 128;
    const int wave = tid >> 6, lane = tid & 63;
    const int wr = (wave >> 1) * 64, wc = (wave & 1) * 64;
    const int lm = lane & 15, lk = (lane >> 4) * 8;
    const int K = DMODEL;

    f32x4_t acc[4][4];
#pragma unroll
    for (int i = 0; i < 4; i++)
#pragma unroll
        for (int j = 0; j < 4; j++)
            acc[i][j] = (f32x4_t){0.f, 0.f, 0.f, 0.f};

    for (int k0 = 0; k0 < K; k0 += 32) {
#pragma unroll
        for (int it = 0; it < 2; ++it) {
            int t = tid + it * 256;
            const unsigned short* gp = A + (size_t)(bm + (t >> 2)) * K + k0 + (t & 3) * 8;
            __builtin_amdgcn_global_load_lds((gas_t)(const char*)gp,
                (las_t)((char*)As + t * 16), 16, 0, 0);
        }
#pragma unroll
        for (int it = 0; it < 2; ++it) {
            int t = tid + it * 256;
            const unsigned short* gp = Bt + (size_t)(bn + (t >> 2)) * K + k0 + (t & 3) * 8;
            __builtin_amdgcn_global_load_lds((gas_t)(const char*)gp,
                (las_t)((char*)Bs + t * 16), 16, 0, 0);
        }
        __syncthreads();
        bf16x8_t af[4], bfr[4];
#pragma unroll
        for (int i = 0; i < 4; i++)
            af[i] = *(const bf16x8_t*)(As + (size_t)(wr + 16 * i + lm) * 32 + lk);
#pragma unroll
        for (int j = 0; j < 4; j++)
            bfr[j] = *(const bf16x8_t*)(Bs + (size_t)(wc + 16 * j + lm) * 32 + lk);
#pragma unroll
        for (int i = 0; i < 4; i++)
#pragma unroll
            for (int j = 0; j < 4; j++)
                acc[i][j] = __builtin_amdgcn_mfma_f32_16x16x32_bf16(af[i], bfr[j], acc[i][j], 0, 0, 0);
        __syncthreads();
    }

    const int sect = bn >> 9;
    const float* bias = (sect == 0) ? bq : (sect == 1) ? bk : bv;
    unsigned short* rowout = (sect == 0) ? Q : Kk;
    const int cb = bn & 511;
    const int col_l = lane & 15;
    const int row_q = (lane >> 4) * 4;
#pragma unroll
    for (int i = 0; i < 4; i++) {
#pragma unroll
        for (int j = 0; j < 4; j++) {
            int cn = cb + wc + 16 * j + col_l;
            float bsv = bias[cn];
            int gm0 = bm + wr + 16 * i + row_q;
            if (sect < 2) {
#pragma unroll
                for (int r = 0; r < 4; r++)
                    rowout[(size_t)(gm0 + r) * DMODEL + cn] = f2bu(acc[i][j][r] + bsv);
            } else {
                int bb_ = gm0 >> 10, ss = gm0 & 1023;
                int hh_ = cn >> 6, dd = cn & 63;
                u16x4 o4;
#pragma unroll
                for (int r = 0; r < 4; r++) o4[r] = f2bu(acc[i][j][r] + bsv);
                *(u16x4*)(vT + (((size_t)(bb_ * NHEAD + hh_) * HDIM + dd) * SEQ + ss)) = o4;
            }
        }
    }
}

// ---------------------------------------------------------------- fused FAVOR K-features + kv accumulate (v5: 4x256-token chunks, bf16 partials)
__global__ __launch_bounds__(256) void favor_k_kv_kernel(
    const unsigned short* __restrict__ Kx,   // [N,DM] bf16
    const unsigned short* __restrict__ vT,   // [BH,64,1024] bf16
    const unsigned short* __restrict__ omT,  // [128][64] bf16 pre-scaled
    unsigned short* __restrict__ kvpart,     // [4][BH][64][256] bf16
    float* __restrict__ kspart)              // [4][BH][256] f32
{
    const int bid = blockIdx.x;
    const int xcd = bid & 7, slot = bid >> 3;    // 512 blocks -> slot 0..63
    const int chunk = slot & 3;
    const int bh = (slot >> 2) * 8 + xcd;
    const int b = bh >> 3, h = bh & 7;
    const int tid = threadIdx.x;
    const int wave = tid >> 6, lane = tid & 63;
    const int lm = lane & 15, q = lane >> 4, lk = q * 8;
    const int quad4 = q * 4;
    const int wr = wave * 64;       // f-rows for kv MFMA
    const int m0 = wave * 16;       // tokens for u MFMA

    __shared__ __align__(16) unsigned short phiT[256 * 72];  // 36 KB [f][m]

    f32x4_t acc_kv[4][4];
#pragma unroll
    for (int i = 0; i < 4; i++)
#pragma unroll
        for (int j = 0; j < 4; j++)
            acc_kv[i][j] = (f32x4_t){0.f, 0.f, 0.f, 0.f};
    float ks_acc = 0.f;

    const unsigned short* vbase = vT + (size_t)bh * HDIM * SEQ;

    for (int st = 0; st < 4; ++st) {
        int s0 = chunk * 256 + st * 64;
        // A-frags from global
        const unsigned short* krow = Kx + (size_t)(b * SEQ + s0 + m0 + lm) * DMODEL + h * HDIM;
        u16x8 xu0 = *(const u16x8*)(krow + lk);
        u16x8 xu1 = *(const u16x8*)(krow + 32 + lk);
        float p = 0.f;
#pragma unroll
        for (int e = 0; e < 8; e++) {
            float a = b2f(xu0[e]), c = b2f(xu1[e]);
            p += a * a + c * c;
        }
        p += __shfl_xor(p, 16, 64);
        p += __shfl_xor(p, 32, 64);
        float hred = 0.5f * SCALE2 * p;      // h for token m0+lm, all lanes
        float hr[4];
#pragma unroll
        for (int r = 0; r < 4; r++) hr[r] = __shfl(hred, quad4 + r, 64);
        // u MFMA
        f32x4_t acc[8];
#pragma unroll
        for (int j = 0; j < 8; j++) acc[j] = (f32x4_t){0.f, 0.f, 0.f, 0.f};
        bf16x8_t af0 = u2b8(xu0), af1 = u2b8(xu1);
#pragma unroll
        for (int j = 0; j < 8; j++) {
            bf16x8_t b0 = *(const bf16x8_t*)(omT + (size_t)(j * 16 + lm) * 64 + lk);
            acc[j] = __builtin_amdgcn_mfma_f32_16x16x32_bf16(af0, b0, acc[j], 0, 0, 0);
            bf16x8_t b1 = *(const bf16x8_t*)(omT + (size_t)(j * 16 + lm) * 64 + 32 + lk);
            acc[j] = __builtin_amdgcn_mfma_f32_16x16x32_bf16(af1, b1, acc[j], 0, 0, 0);
        }
        __syncthreads();   // prior phiT readers done before overwrite
        // epilogue: phi -> phiT [f][m]
#pragma unroll
        for (int j = 0; j < 8; j++) {
            int f = j * 16 + lm;
#pragma unroll
            for (int r = 0; r < 4; r++) {
                int m = m0 + quad4 + r;
                float u = acc[j][r];
                phiT[f * 72 + m]         = f2bu(__expf(u - hr[r]) * FSCALE);
                phiT[(f + 128) * 72 + m] = f2bu(__expf(-u - hr[r]) * FSCALE);
            }
        }
        __syncthreads();   // phiT ready
        // ksum partial: thread owns feature f = tid
        {
            const unsigned short* row = &phiT[tid * 72];
#pragma unroll
            for (int mm = 0; mm < 64; mm += 8) {
                u16x8 v = *(const u16x8*)(row + mm);
#pragma unroll
                for (int e = 0; e < 8; e++) ks_acc += b2f(v[e]);
            }
        }
        // kv MFMA: A = phiT [f][s], B = vT [d][s] (global)
#pragma unroll
        for (int ks = 0; ks < 2; ks++) {
            bf16x8_t af[4], bfr[4];
#pragma unroll
            for (int i = 0; i < 4; i++)
                af[i] = *(const bf16x8_t*)&phiT[(wr + 16 * i + lm) * 72 + ks * 32 + lk];
#pragma unroll
            for (int j = 0; j < 4; j++)
                bfr[j] = *(const bf16x8_t*)(vbase + (size_t)(16 * j + lm) * SEQ + s0 + ks * 32 + lk);
#pragma unroll
            for (int i = 0; i < 4; i++)
#pragma unroll
                for (int j = 0; j < 4; j++)
                    acc_kv[i][j] = __builtin_amdgcn_mfma_f32_16x16x32_bf16(af[i], bfr[j], acc_kv[i][j], 0, 0, 0);
        }
    }

    // write kv partial (bf16): layout [chunk][bh][d][f]
    unsigned short* kp = kvpart + ((size_t)chunk * BH_TOT + bh) * HDIM * FDIM;
#pragma unroll
    for (int i = 0; i < 4; i++) {
#pragma unroll
        for (int j = 0; j < 4; j++) {
            int d = 16 * j + lm;
            int f0 = wr + 16 * i + quad4;
            u16x4 o4;
#pragma unroll
            for (int r = 0; r < 4; r++) o4[r] = f2bu(acc_kv[i][j][r]);
            *(u16x4*)(kp + (size_t)d * FDIM + f0) = o4;
        }
    }
    kspart[(size_t)chunk * (BH_TOT * FDIM) + (size_t)bh * FDIM + tid] = ks_acc;
}

// ---------------------------------------------------------------- reduce 4 bf16 kv partials -> bf16 kvT; 4 f32 ks partials -> f32 ksum
__global__ __launch_bounds__(256) void reduce_kv_kernel(
    const unsigned short* __restrict__ in_kv, const float* __restrict__ in_ks,
    unsigned short* __restrict__ out_kv, float* __restrict__ out_ks)
{
    const int NKV = BH_TOT * HDIM * FDIM;   // 2097152
    const int NKS = BH_TOT * FDIM;          // 32768
    int blk = blockIdx.x;
    if (blk < 1024) {
        size_t base = ((size_t)blk * 256 + threadIdx.x) * 8;
        u16x8 v0 = *(const u16x8*)(in_kv + base);
        u16x8 v1 = *(const u16x8*)(in_kv + base + NKV);
        u16x8 v2 = *(const u16x8*)(in_kv + base + 2 * (size_t)NKV);
        u16x8 v3 = *(const u16x8*)(in_kv + base + 3 * (size_t)NKV);
        u16x8 o;
#pragma unroll
        for (int e = 0; e < 8; e++)
            o[e] = f2bu(b2f(v0[e]) + b2f(v1[e]) + b2f(v2[e]) + b2f(v3[e]));
        *(u16x8*)(out_kv + base) = o;
    } else {
        size_t j = ((size_t)(blk - 1024) * 256 + threadIdx.x) * 4;
        float4 a0 = *(const float4*)(in_ks + j);
        float4 a1 = *(const float4*)(in_ks + j + NKS);
        float4 a2 = *(const float4*)(in_ks + j + 2 * (size_t)NKS);
        float4 a3 = *(const float4*)(in_ks + j + 3 * (size_t)NKS);
        float4 o = make_float4(a0.x + a1.x + a2.x + a3.x, a0.y + a1.y + a2.y + a3.y,
                               a0.z + a1.z + a2.z + a3.z, a0.w + a1.w + a2.w + a3.w);
        *(float4*)(out_ks + j) = o;
    }
}

// ---------------------------------------------------------------- fused FAVOR Q-features + attention (v8: shared kss, zero barriers)
__global__ __launch_bounds__(256) void favor_q_attn_kernel(
    const unsigned short* __restrict__ Qx,   // [N,DM] bf16
    const unsigned short* __restrict__ omT,  // [128][64] bf16 pre-scaled
    const unsigned short* __restrict__ kvT,  // [BH,64,256] bf16
    const float* __restrict__ ksum,          // [BH,256] f32
    unsigned short* __restrict__ outX)       // [N,DM] bf16
{
    const int bid = blockIdx.x;
    const int xcd = bid & 7, slot = bid >> 3;   // 2048 blocks -> slot 0..255
    const int sc = slot & 15;
    const int bh = (slot >> 4) * 8 + xcd;       // all 16 tiles of a bh share one XCD
    const int b = bh >> 3, h = bh & 7;
    const int s0 = sc * 64;
    const int tid = threadIdx.x;
    const int wave = tid >> 6, lane = tid & 63;
    const int lm = lane & 15, q = lane >> 4, lk = q * 8;
    const int quad4 = q * 4;
    const int m0 = wave * 16;

    __shared__ __align__(16) unsigned short phis[4][16 * 136]; // 17.4 KB per-wave slices
    __shared__ __align__(16) float kss[256];                   // 1 KB shared (identical writes)

    // every wave writes the full copy -> no cross-wave dependency, no barrier
    *(float4*)&kss[lane * 4] = *(const float4*)(ksum + (size_t)bh * FDIM + lane * 4);

    // Q A-frags from global
    const unsigned short* qrow = Qx + (size_t)(b * SEQ + s0 + m0 + lm) * DMODEL + h * HDIM;
    u16x8 xu0 = *(const u16x8*)(qrow + lk);
    u16x8 xu1 = *(const u16x8*)(qrow + 32 + lk);
    float p = 0.f;
#pragma unroll
    for (int e = 0; e < 8; e++) {
        float a = b2f(xu0[e]), c = b2f(xu1[e]);
        p += a * a + c * c;
    }
    p += __shfl_xor(p, 16, 64);
    p += __shfl_xor(p, 32, 64);
    float hred = 0.5f * SCALE2 * p;          // h for token m0+lm
    float hr[4];
#pragma unroll
    for (int r = 0; r < 4; r++) hr[r] = __shfl(hred, quad4 + r, 64);

    // u MFMA
    f32x4_t acc[8];
#pragma unroll
    for (int j = 0; j < 8; j++) acc[j] = (f32x4_t){0.f, 0.f, 0.f, 0.f};
    bf16x8_t af0 = u2b8(xu0), af1 = u2b8(xu1);
#pragma unroll
    for (int j = 0; j < 8; j++) {
        bf16x8_t b0 = *(const bf16x8_t*)(omT + (size_t)(j * 16 + lm) * 64 + lk);
        acc[j] = __builtin_amdgcn_mfma_f32_16x16x32_bf16(af0, b0, acc[j], 0, 0, 0);
        bf16x8_t b1 = *(const bf16x8_t*)(omT + (size_t)(j * 16 + lm) * 64 + 32 + lk);
        acc[j] = __builtin_amdgcn_mfma_f32_16x16x32_bf16(af1, b1, acc[j], 0, 0, 0);
    }

    // pass-1 epilogue: phi+ -> own LDS slice; z accumulated in registers
    unsigned short* ph = phis[wave];
    float zp[4] = {0.f, 0.f, 0.f, 0.f};
#pragma unroll
    for (int j = 0; j < 8; j++) {
        int f = j * 16 + lm;
        float ksp = kss[f], ksm = kss[128 + f];
#pragma unroll
        for (int r = 0; r < 4; r++) {
            float u = acc[j][r];
            float pp = __expf(u - hr[r]) * FSCALE;
            float pm = __expf(-u - hr[r]) * FSCALE;
            ph[(quad4 + r) * 136 + f] = f2bu(pp);
            zp[r] += pp * ksp + pm * ksm;
        }
    }
#pragma unroll
    for (int off = 1; off < 16; off <<= 1) {
        zp[0] += __shfl_xor(zp[0], off, 64);
        zp[1] += __shfl_xor(zp[1], off, 64);
        zp[2] += __shfl_xor(zp[2], off, 64);
        zp[3] += __shfl_xor(zp[3], off, 64);
    }
    float zinv[4];
#pragma unroll
    for (int r = 0; r < 4; r++) zinv[r] = 1.f / (zp[r] + 1e-6f);

    const unsigned short* kvbase = kvT + (size_t)bh * HDIM * FDIM;
    f32x4_t acc_o[4];
#pragma unroll
    for (int j = 0; j < 4; j++) acc_o[j] = (f32x4_t){0.f, 0.f, 0.f, 0.f};
    // pass 1: features [0,128)
#pragma unroll
    for (int k0 = 0; k0 < 128; k0 += 32) {
        bf16x8_t af = *(const bf16x8_t*)&ph[lm * 136 + k0 + lk];
#pragma unroll
        for (int j = 0; j < 4; j++) {
            bf16x8_t bfr = *(const bf16x8_t*)(kvbase + (size_t)(16 * j + lm) * FDIM + k0 + lk);
            acc_o[j] = __builtin_amdgcn_mfma_f32_16x16x32_bf16(af, bfr, acc_o[j], 0, 0, 0);
        }
    }
    // pass-2 epilogue: overwrite own slice with phi- (recompute exp; keeps VGPR <= 64)
#pragma unroll
    for (int j = 0; j < 8; j++) {
        int f = j * 16 + lm;
#pragma unroll
        for (int r = 0; r < 4; r++)
            ph[(quad4 + r) * 136 + f] = f2bu(__expf(-acc[j][r] - hr[r]) * FSCALE);
    }
    // pass 2: features [128,256)
#pragma unroll
    for (int k0 = 0; k0 < 128; k0 += 32) {
        bf16x8_t af = *(const bf16x8_t*)&ph[lm * 136 + k0 + lk];
#pragma unroll
        for (int j = 0; j < 4; j++) {
            bf16x8_t bfr = *(const bf16x8_t*)(kvbase + (size_t)(16 * j + lm) * FDIM + 128 + k0 + lk);
            acc_o[j] = __builtin_amdgcn_mfma_f32_16x16x32_bf16(af, bfr, acc_o[j], 0, 0, 0);
        }
    }
    // epilogue: scale by z, store
#pragma unroll
    for (int r = 0; r < 4; r++) {
        int s = s0 + m0 + quad4 + r;
#pragma unroll
        for (int j = 0; j < 4; j++) {
            int d = 16 * j + lm;
            outX[(size_t)(b * SEQ + s) * DMODEL + h * HDIM + d] = f2bu(acc_o[j][r] * zinv[r]);
        }
    }
}

// ---------------------------------------------------------------- residual + LayerNorm (wave-per-row, zero barriers, zero LDS)
template<int HAS_RES>
__global__ __launch_bounds__(512) void add_ln_kernel(
    const unsigned short* __restrict__ res16, const unsigned short* __restrict__ tin16,
    const float* __restrict__ g, const float* __restrict__ bb,
    unsigned short* __restrict__ out16)
{
    int wave = threadIdx.x >> 6, lane = threadIdx.x & 63;
    int row = blockIdx.x * 8 + wave;
    size_t base = (size_t)row * DMODEL + lane * 8;
    u16x8 tv = *(const u16x8*)(tin16 + base);
    float v[8];
    float s1 = 0.f, s2 = 0.f;
    if (HAS_RES) {
        u16x8 rv = *(const u16x8*)(res16 + base);
#pragma unroll
        for (int e = 0; e < 8; e++) v[e] = b2f(tv[e]) + b2f(rv[e]);
    } else {
#pragma unroll
        for (int e = 0; e < 8; e++) v[e] = b2f(tv[e]);
    }
#pragma unroll
    for (int e = 0; e < 8; e++) { s1 += v[e]; s2 += v[e] * v[e]; }
#pragma unroll
    for (int off = 1; off < 64; off <<= 1) {
        s1 += __shfl_xor(s1, off, 64);
        s2 += __shfl_xor(s2, off, 64);
    }
    float m = s1 * (1.f / DMODEL);
    float var = s2 * (1.f / DMODEL) - m * m;
    float r = rsqrtf(var + 1e-5f);
    float4 g0 = *(const float4*)(g + lane * 8);
    float4 g1 = *(const float4*)(g + lane * 8 + 4);
    float4 b0 = *(const float4*)(bb + lane * 8);
    float4 b1 = *(const float4*)(bb + lane * 8 + 4);
    float gg[8] = {g0.x, g0.y, g0.z, g0.w, g1.x, g1.y, g1.z, g1.w};
    float bbv[8] = {b0.x, b0.y, b0.z, b0.w, b1.x, b1.y, b1.z, b1.w};
    u16x8 o;
#pragma unroll
    for (int e = 0; e < 8; e++)
        o[e] = f2bu((v[e] - m) * r * gg[e] + bbv[e]);
    *(u16x8*)(out16 + base) = o;
}

// ---------------------------------------------------------------- pool stage 1
__global__ __launch_bounds__(256) void pool_part_kernel(
    const unsigned short* __restrict__ h16, float* __restrict__ pbuf)
{
    int blk = blockIdx.x;
    int b = blk >> 4, ch = blk & 15;
    int t = threadIdx.x;
    int d0 = t * 2;
    float a0 = 0.f, a1 = 0.f;
    const unsigned short* base = h16 + ((size_t)(b * SEQ + ch * 64) * DMODEL) + d0;
#pragma unroll 4
    for (int s = 0; s < 64; s++) {
        ushort2 v = *(const ushort2*)(base + (size_t)s * DMODEL);
        a0 += b2f(v.x); a1 += b2f(v.y);
    }
    *(float2*)(pbuf + (size_t)blk * DMODEL + d0) = make_float2(a0, a1);
}

// ---------------------------------------------------------------- pool stage 2 + classify
__global__ __launch_bounds__(512) void cls_kernel(
    const float* __restrict__ pbuf, const float* __restrict__ cls_w,
    const float* __restrict__ cls_b, float* __restrict__ out)
{
    int b = blockIdx.x, t = threadIdx.x;
    float s = 0.f;
#pragma unroll
    for (int c = 0; c < 16; c++) s += pbuf[(size_t)(b * 16 + c) * DMODEL + t];
    __shared__ float pooled[DMODEL];
    pooled[t] = s * (1.f / SEQ);
    __syncthreads();
    if (t < 16) {
        float acc = cls_b[t];
        for (int c = 0; c < DMODEL; c++) acc += pooled[c] * cls_w[c * 16 + t];
        out[b * 16 + t] = acc;
    }
}

// ----------------------------------------------------------------
extern "C" void kernel_launch(void* const* d_in, const int* in_sizes, int n_in,
                              void* d_out, int out_size, void* d_ws, size_t ws_size,
                              hipStream_t stream)
{
    const float* x      = (const float*)d_in[0];
    const float* pos    = (const float*)d_in[1];
    const float* enc_w1 = (const float*)d_in[2];
    const float* enc_b1 = (const float*)d_in[3];
    const float* enc_w2 = (const float*)d_in[4];
    const float* enc_b2 = (const float*)d_in[5];
    const float* enc_g  = (const float*)d_in[6];
    const float* enc_bb = (const float*)d_in[7];
    const float* wq = (const float*)d_in[8];
    const float* bq = (const float*)d_in[9];
    const float* wk = (const float*)d_in[10];
    const float* bk = (const float*)d_in[11];
    const float* wv = (const float*)d_in[12];
    const float* bv = (const float*)d_in[13];
    const float* wo = (const float*)d_in[14];
    const float* bo = (const float*)d_in[15];
    const float* ln1_g = (const float*)d_in[16];
    const float* ln1_b = (const float*)d_in[17];
    const float* w1 = (const float*)d_in[18];
    const float* b1 = (const float*)d_in[19];
    const float* w2 = (const float*)d_in[20];
    const float* b2 = (const float*)d_in[21];
    const float* ln2_g = (const float*)d_in[22];
    const float* ln2_b = (const float*)d_in[23];
    const float* omega = (const float*)d_in[24];
    const float* cls_w = (const float*)d_in[25];
    const float* cls_b = (const float*)d_in[26];
    float* out = (float*)d_out;

    const int N = NTOK;
    const int BH = BH_TOT;

    char* p = (char*)d_ws;
    unsigned short* qb16 = (unsigned short*)p; p += (size_t)N * DMODEL * 2;   // 16MB
    unsigned short* kb16 = (unsigned short*)p; p += (size_t)N * DMODEL * 2;   // 16MB
    unsigned short* vT16 = (unsigned short*)p; p += (size_t)N * DMODEL * 2;   // 16MB
    unsigned short* h16  = (unsigned short*)p; p += (size_t)N * DMODEL * 2;   // 16MB
    unsigned short* mid16 = (unsigned short*)p; p += (size_t)N * 1024 * 2;    // 32MB
    unsigned short* attn16 = (unsigned short*)p; p += (size_t)N * DMODEL * 2; // 16MB
    unsigned short* kvpart = (unsigned short*)p; p += (size_t)4 * BH * HDIM * FDIM * 2; // 16.8MB
    float* kspart = (float*)p;                 p += (size_t)4 * BH * FDIM * 4;          // 512KB
    unsigned short* kvT16 = (unsigned short*)p; p += (size_t)BH * HDIM * FDIM * 2;      // 4MB
    float* ksb = (float*)p;                    p += (size_t)BH * FDIM * 4;    // 128KB
    float* pbuf = (float*)p;                   p += (size_t)BATCH * 16 * DMODEL * 4;    // 512KB
    unsigned short* enc_w2t = (unsigned short*)p; p += (size_t)256 * 512 * 2;
    unsigned short* wqkvt = (unsigned short*)p; p += (size_t)4 * 1536 * 512 * 2;  // 6MB
    unsigned short* wot = (unsigned short*)p;  p += (size_t)4 * 512 * 512 * 2;
    unsigned short* w1t = (unsigned short*)p;  p += (size_t)4 * 512 * 1024 * 2;
    unsigned short* w2t = (unsigned short*)p;  p += (size_t)4 * 1024 * 512 * 2;
    unsigned short* omT = (unsigned short*)p;  p += (size_t)4 * 128 * 64 * 2;

    // ---- all weight conversion in one dispatch ----
    convT_all_kernel<<<8448, 256, 0, stream>>>(
        enc_w2, wq, wk, wv, wo, w1, w2, omega,
        enc_w2t, wqkvt, wot, w1t, w2t, omT);

    // ---- encoder ----
    enc1_kernel<<<N / 8, 256, 0, stream>>>(x, pos, enc_w1, enc_b1, mid16);
    gemm_bf16_n64_kernel<0><<<8 * 128, 256, 0, stream>>>(mid16, enc_w2t, enc_b2, qb16, N, 256, 512, 8);
    add_ln_kernel<0><<<N / 8, 512, 0, stream>>>(nullptr, qb16, enc_g, enc_bb, h16);

    // ---- layers ----
    for (int l = 0; l < 4; l++) {
        const unsigned short* omT_l = omT + (size_t)l * 8192;
        gemm_qkv_kernel<<<12 * 128, 256, 0, stream>>>(
            h16, wqkvt + (size_t)l * 786432,
            bq + l * DMODEL, bk + l * DMODEL, bv + l * DMODEL,
            qb16, kb16, vT16);
        favor_k_kv_kernel<<<BH * 4, 256, 0, stream>>>(kb16, vT16, omT_l, kvpart, kspart);
        reduce_kv_kernel<<<1056, 256, 0, stream>>>(kvpart, kspart, kvT16, ksb);
        favor_q_attn_kernel<<<BH * 16, 256, 0, stream>>>(qb16, omT_l, kvT16, ksb, attn16);
        gemm_bf16_n64_kernel<0><<<8 * 128, 256, 0, stream>>>(attn16, wot + (size_t)l * 262144, bo + l * DMODEL, qb16, N, 512, 512, 8);
        add_ln_kernel<1><<<N / 8, 512, 0, stream>>>(h16, qb16, ln1_g + l * DMODEL, ln1_b + l * DMODEL, h16);
        gemm_bf16_n64_kernel<1><<<16 * 128, 256, 0, stream>>>(h16, w1t + (size_t)l * 524288, b1 + l * 1024, mid16, N, 512, 1024, 16);
        gemm_bf16_n64_kernel<0><<<8 * 128, 256, 0, stream>>>(mid16, w2t + (size_t)l * 524288, b2 + l * DMODEL, qb16, N, 1024, 512, 8);
        add_ln_kernel<1><<<N / 8, 512, 0, stream>>>(h16, qb16, ln2_g + l * DMODEL, ln2_b + l * DMODEL, h16);
    }

    // ---- pool + classify ----
    pool_part_kernel<<<BATCH * 16, 256, 0, stream>>>(h16, pbuf);
    cls_kernel<<<BATCH, 512, 0, stream>>>(pbuf, cls_w, cls_b, out);
}